// Round 9
// baseline (3903.666 us; speedup 1.0000x reference)
//
#include <hip/hip_runtime.h>
#include <hip/hip_bf16.h>
#include <stdint.h>

typedef __bf16 bf16_t;
typedef __bf16 bf16x8 __attribute__((ext_vector_type(8)));
typedef __bf16 bf16x4_t __attribute__((ext_vector_type(4)));
typedef float f32x4 __attribute__((ext_vector_type(4)));

#define AS1 __attribute__((address_space(1)))
#define AS3 __attribute__((address_space(3)))

__device__ __forceinline__ void stage16(const bf16_t* g, char* l) {
    __builtin_amdgcn_global_load_lds((const AS1 uint32_t*)g, (AS3 uint32_t*)l, 16, 0, 0);
}

#define BAR()   __builtin_amdgcn_s_barrier()
#define LGKM0() asm volatile("s_waitcnt lgkmcnt(0)" ::: "memory")
#define VMC(N)  asm volatile("s_waitcnt vmcnt(" #N ")" ::: "memory")
#define PRIO(p) __builtin_amdgcn_s_setprio(p)

// ----------------------------------------------------------------------------
// 256x256 bf16 GEMM, BK=32 x 2 buffers = 64KB LDS -> TWO BLOCKS PER CU.
// R8 diagnosis: at 128KB LDS (1 block/CU) all waves drain/barrier together and
// the matrix pipe idles -> 51% MfmaUtil plateau across 3 schedule variants.
// Cross-block TLP (m114-verified) fills those gaps: when block A stalls at
// VMC(0)/barrier, block B's waves keep the MFMA pipe fed.
// 512 thr = 8 waves (2Mx4N), per-wave 128x64; st_16x32 swizzle via
// pre-swizzled global source + XOR'd ds_read (unchanged).
//
// 4 phases per K=64 iter (16 MFMA/phase, reads 8/4/8/4):
//  P1: STG b1-this(A+B,@kB) | RDB4(0)+RDA2(0,0)+RDA2(0,1) |        LGKM0 BAR | MF0 MF1
//  P2:                      | RDA2(0,2)+RDA2(0,3)         | VMC(0) LGKM0 BAR | MF2 MF3
//  P3: STG b0-next(A+B,@kN) | RDB4(1)+RDA2(1,0)+RDA2(1,1) |        LGKM0 BAR | MF0 MF1
//  P4:                      | RDA2(1,2)+RDA2(1,3)         | VMC(0) LGKM0 BAR | MF2 MF3
// Certification: VMC(0)@P2 retires P1's b1 stage before P3 reads it;
// VMC(0)@P4 retires P3's b0-next stage before next-P1 reads. Overwrite
// safety: b1 last read drains pre-BAR(P4-prev) < P1-stage; b0 pre-BAR(P2) <
// P3-stage. Full drains are tolerable BECAUSE the co-resident block absorbs.
// Registers: bfr[4]+afA/afB = 32 VGPR operand state (was 48) -> fits 4
// waves/SIMD at the 128-VGPR step; __launch_bounds__(512,4) enforces.
// Epilogue: LDS-staged coalesced C in 64KB chunks (2x128 rows bf16 /
// 4x64 rows fp32), quad-XOR bank swizzle (R3-verified, WRITE_SIZE ideal).
// ----------------------------------------------------------------------------
template <typename OutT>
__global__ __launch_bounds__(512, 4) void gemm256(
    const bf16_t* __restrict__ A, int lda,
    const bf16_t* __restrict__ Bt, int ldb,
    const float* __restrict__ bias,
    OutT* __restrict__ C, int ldc,
    int K, int nTilesN)
{
    __shared__ char smem[65536];
    const int tid  = threadIdx.x;
    const int wave = tid >> 6;
    const int lane = tid & 63;
    const int wm = wave >> 2;   // 0..1 -> rows wm*128..+128
    const int wn = wave & 3;    // 0..3 -> cols wn*64..+64

    // XCD-aware bijective swizzle (gridDim.x % 8 == 0 guaranteed by caller)
    const int bid = blockIdx.x;
    const int swz = (bid & 7) * ((int)gridDim.x >> 3) + (bid >> 3);
    const int m0 = (swz / nTilesN) << 8;
    const int n0 = (swz % nTilesN) << 8;

    // Staging source: wave w covers row-groups 2w,2w+1 of the 256-row tile;
    // lane 16B chunk col = (lane&3)*8, XOR 16 when subtile row bit 3 set
    // (inverse st_16x32 pre-swizzle on the global source address).
    const int srow = lane >> 2;
    const int scol = ((lane & 3) * 8) ^ ((lane & 32) >> 1);
    const bf16_t* aS0 = A  + (size_t)(m0 + wave * 32 + srow) * lda + scol;
    const bf16_t* aS1 = aS0 + (size_t)16 * lda;
    const bf16_t* bS0 = Bt + (size_t)(n0 + wave * 32 + srow) * ldb + scol;
    const bf16_t* bS1 = bS0 + (size_t)16 * ldb;

    // LDS map: A(b) = b*32768 ; B(b) = b*32768 + 16384. (BK=32: 16KB each.)
#define STAGE_A(b,kb) do { \
    stage16(aS0 + (kb), smem + (b)*32768 + wave*2048); \
    stage16(aS1 + (kb), smem + (b)*32768 + wave*2048 + 1024); } while(0)
#define STAGE_B(b,kb) do { \
    stage16(bS0 + (kb), smem + (b)*32768 + 16384 + wave*2048); \
    stage16(bS1 + (kb), smem + (b)*32768 + 16384 + wave*2048 + 1024); } while(0)

    // ds_read: lane l -> row l&15, k-chunk (l>>4)*16B, with st_16x32 XOR.
    const int rdLane = (lane & 15) * 64 + (((lane >> 4) * 16) ^ ((lane & 8) << 2));
    const char* aRdB = smem + rdLane + wm * 8192;            // + mi*1024 + b*32768
    const char* bRdB = smem + 16384 + rdLane + wn * 4096;    // + ni*1024 + b*32768

    f32x4 acc[8][4];
#pragma unroll
    for (int i = 0; i < 8; ++i)
#pragma unroll
        for (int j = 0; j < 4; ++j) acc[i][j] = (f32x4){0.f, 0.f, 0.f, 0.f};
    bf16x8 bfr[4];        // [ni] B-frags for current buffer
    bf16x8 afA[2], afB[2];// A-frag pairs for the two mp's of this phase

#define RDB4(b) { _Pragma("unroll") \
    for (int ni = 0; ni < 4; ++ni) \
        bfr[ni] = *(const bf16x8*)(bRdB + (b)*32768 + ni*1024); }
#define RDA2(b,mp,dst) { _Pragma("unroll") \
    for (int t = 0; t < 2; ++t) \
        dst[t] = *(const bf16x8*)(aRdB + (b)*32768 + ((mp)*2+t)*1024); }
#define MF(mp,src) { _Pragma("unroll") \
    for (int t = 0; t < 2; ++t) _Pragma("unroll") \
        for (int ni = 0; ni < 4; ++ni) \
            acc[(mp)*2+t][ni] = __builtin_amdgcn_mfma_f32_16x16x32_bf16(src[t], bfr[ni], acc[(mp)*2+t][ni], 0, 0, 0); }
#define PH(STG, RDS, WAIT, MFM) do { \
    STG; RDS; WAIT; LGKM0(); BAR(); PRIO(1); MFM; PRIO(0); } while(0)

    // Prologue: b0 @k=0 (4 loads), drain, barrier.
    STAGE_A(0, 0); STAGE_B(0, 0);
    VMC(0);
    BAR();

    const int NI = K >> 6;
    for (int it = 0; it < NI - 1; ++it) {
        const int kB = (it << 6) + 32;   // this iter's b1
        const int kN = (it << 6) + 64;   // next iter's b0
        PH(STAGE_A(1,kB); STAGE_B(1,kB), RDB4(0); RDA2(0,0,afA); RDA2(0,1,afB), ,       MF(0,afA); MF(1,afB));
        PH(,                             RDA2(0,2,afA); RDA2(0,3,afB),          VMC(0), MF(2,afA); MF(3,afB));
        PH(STAGE_A(0,kN); STAGE_B(0,kN), RDB4(1); RDA2(1,0,afA); RDA2(1,1,afB), ,       MF(0,afA); MF(1,afB));
        PH(,                             RDA2(1,2,afA); RDA2(1,3,afB),          VMC(0), MF(2,afA); MF(3,afB));
    }
    // Epilogue iteration: stage only b1-this; no next-tile stages.
    {
        const int kB = ((NI - 1) << 6) + 32;
        PH(STAGE_A(1,kB); STAGE_B(1,kB), RDB4(0); RDA2(0,0,afA); RDA2(0,1,afB), ,       MF(0,afA); MF(1,afB));
        PH(,                             RDA2(0,2,afA); RDA2(0,3,afB),          VMC(0), MF(2,afA); MF(3,afB));
        PH(,                             RDB4(1); RDA2(1,0,afA); RDA2(1,1,afB), ,       MF(0,afA); MF(1,afB));
        PH(,                             RDA2(1,2,afA); RDA2(1,3,afB),          ,       MF(2,afA); MF(3,afB));
    }
    BAR();

    // ---- Epilogue: LDS-staged coalesced C write in 64KB chunks ----
    // bf16: 2 chunks x 128 rows; fp32: 4 chunks x 64 rows.
    // Write-in swizzle: colb ^= quad*16*CSZ; readback same XOR (q2 from lrow).
    {
        const int mrow = lane & 15;
        const int quad = lane >> 4;
        constexpr int CSZ = (int)sizeof(OutT);
        constexpr int CH_ROWS = 65536 / (256 * CSZ);
        constexpr int NCH = 256 / CH_ROWS;
        float bias_v[4];
#pragma unroll
        for (int ni = 0; ni < 4; ++ni)
            bias_v[ni] = bias[n0 + wn * 64 + ni * 16 + mrow];
#pragma unroll
        for (int ch = 0; ch < NCH; ++ch) {
            const int rowBase = ch * CH_ROWS;
            if (wm == rowBase / 128) {
                const int miLo = (rowBase % 128) / 16;
#pragma unroll
                for (int ni = 0; ni < 4; ++ni) {
                    const int colb = (wn * 64 + ni * 16 + mrow) * CSZ;
#pragma unroll
                    for (int mi2 = 0; mi2 < CH_ROWS / 16; ++mi2) {
                        const int mi = miLo + mi2;
#pragma unroll
                        for (int r = 0; r < 4; ++r) {
                            const int lrow = mi2 * 16 + quad * 4 + r;
                            *(OutT*)(smem + lrow * 256 * CSZ + (colb ^ (quad * 16 * CSZ))) =
                                (OutT)(acc[mi][ni][r] + bias_v[ni]);
                        }
                    }
                }
            }
            BAR();
            const int ROUNDS = CH_ROWS * 256 * CSZ / 8192;
#pragma unroll
            for (int rd = 0; rd < ROUNDS; ++rd) {
                const int flat = rd * 8192 + tid * 16;
                const int lrow = flat / (256 * CSZ);
                const int colb = flat % (256 * CSZ);
                const int q2 = (lrow >> 2) & 3;
                uint4 v = *(const uint4*)(smem + lrow * 256 * CSZ + (colb ^ (q2 * 16 * CSZ)));
                *(uint4*)((char*)C + ((size_t)(m0 + rowBase + lrow) * ldc + n0) * CSZ + colb) = v;
            }
            BAR();
        }
    }
#undef STAGE_A
#undef STAGE_B
#undef RDB4
#undef RDA2
#undef MF
#undef PH
}

// ----------------------------------------------------------------------------
// Merged prep: ONE launch (f32->bf16 + 4 transposes + concat_bias). R8-verified.
// ----------------------------------------------------------------------------
__global__ __launch_bounds__(256) void prep(
    const float* __restrict__ hs, bf16_t* __restrict__ hs_b,
    const float* __restrict__ Wq, const float* __restrict__ Wk,
    const float* __restrict__ Wv, const float* __restrict__ Wo,
    bf16_t* __restrict__ Wt, bf16_t* __restrict__ Wot,
    const float* __restrict__ bq, const float* __restrict__ bk,
    const float* __restrict__ bv, float* __restrict__ bqkv)
{
    __shared__ bf16_t t[64][65];
    const int b = blockIdx.x;
    if (b < 4096) {
        size_t i = (size_t)b * 256 + threadIdx.x;
#pragma unroll
        for (int r = 0; r < 8; ++r, i += 1048576) {
            float4 v = ((const float4*)hs)[i];
            bf16x4_t o;
            o.x = (bf16_t)v.x; o.y = (bf16_t)v.y; o.z = (bf16_t)v.z; o.w = (bf16_t)v.w;
            ((bf16x4_t*)hs_b)[i] = o;
        }
        return;
    }
    if (b >= 6656) {
        int i = (b - 6656) * 256 + threadIdx.x;
        if (i < 3072) bqkv[i] = (i < 2048) ? bq[i] : (i < 2560 ? bk[i - 2048] : bv[i - 2560]);
        return;
    }
    const float* src; bf16_t* dst; int cols, bx, by;
    if (b < 5120)      { src = Wq; dst = Wt;                     cols = 2048; int u = b - 4096; bx = u & 31; by = u >> 5; }
    else if (b < 5376) { src = Wk; dst = Wt + (size_t)2048*2048; cols = 512;  int u = b - 5120; bx = u & 7;  by = u >> 3; }
    else if (b < 5632) { src = Wv; dst = Wt + (size_t)2560*2048; cols = 512;  int u = b - 5376; bx = u & 7;  by = u >> 3; }
    else               { src = Wo; dst = Wot;                    cols = 2048; int u = b - 5632; bx = u & 31; by = u >> 5; }
    const int rows = 2048;
    const int tx = threadIdx.x & 63;
    const int ty = threadIdx.x >> 6;
    const int c0 = bx * 64;
    const int r0 = by * 64;
#pragma unroll
    for (int r = ty; r < 64; r += 4)
        t[r][tx] = (bf16_t)src[(size_t)(r0 + r) * cols + c0 + tx];
    __syncthreads();
#pragma unroll
    for (int r = ty; r < 64; r += 4)
        dst[(size_t)(c0 + r) * rows + r0 + tx] = t[tx][r];
}

// ----------------------------------------------------------------------------
// Shuffle-free grouped attention: ONE THREAD per (token, head). Zero cross-
// lane ops, zero LDS (R7-verified). Writes compact [16384][2048] (so=2048).
// ----------------------------------------------------------------------------
__global__ __launch_bounds__(256) void gqa_attn(
    const bf16_t* __restrict__ qkv, int sq,
    bf16_t* __restrict__ out, int so)
{
    const int t = blockIdx.x * 256 + threadIdx.x;
    const int token = t >> 4;
    const int h = t & 15;
    const bf16_t* qb = qkv + (size_t)token * sq + h * 128;
    const bf16_t* kb = qkv + (size_t)token * sq + 2048;
    const bf16_t* vb = kb + 512;
    const float scale = 0.08838834764831845f;  // 1/sqrt(128)

    float s[4] = {0.f, 0.f, 0.f, 0.f};
#pragma unroll 4
    for (int c = 0; c < 16; ++c) {
        const uint4 qv = *(const uint4*)(qb + c * 8);
        const uint32_t qa[4] = {qv.x, qv.y, qv.z, qv.w};
#pragma unroll
        for (int g = 0; g < 4; ++g) {
            const uint4 kv4 = *(const uint4*)(kb + g * 128 + c * 8);
            const uint32_t ka[4] = {kv4.x, kv4.y, kv4.z, kv4.w};
#pragma unroll
            for (int w = 0; w < 4; ++w) {
                s[g] += __uint_as_float(qa[w] << 16) * __uint_as_float(ka[w] << 16);
                s[g] += __uint_as_float(qa[w] & 0xffff0000u) * __uint_as_float(ka[w] & 0xffff0000u);
            }
        }
    }
    const float mx = fmaxf(fmaxf(s[0], s[1]), fmaxf(s[2], s[3]));
    float p[4], sum = 0.f;
#pragma unroll
    for (int g = 0; g < 4; ++g) { p[g] = __expf((s[g] - mx) * scale); sum += p[g]; }
    const float rs = 1.0f / sum;
#pragma unroll
    for (int g = 0; g < 4; ++g) p[g] *= rs;

    bf16_t* ob = out + (size_t)token * so + h * 128;
#pragma unroll 4
    for (int c = 0; c < 16; ++c) {
        float o0[8] = {0.f, 0.f, 0.f, 0.f, 0.f, 0.f, 0.f, 0.f};
#pragma unroll
        for (int g = 0; g < 4; ++g) {
            const uint4 vv = *(const uint4*)(vb + g * 128 + c * 8);
            const uint32_t va[4] = {vv.x, vv.y, vv.z, vv.w};
#pragma unroll
            for (int w = 0; w < 4; ++w) {
                o0[w * 2]     += p[g] * __uint_as_float(va[w] << 16);
                o0[w * 2 + 1] += p[g] * __uint_as_float(va[w] & 0xffff0000u);
            }
        }
        bf16x8 ov;
#pragma unroll
        for (int j = 0; j < 8; ++j) ov[j] = (bf16_t)o0[j];
        *(bf16x8*)(ob + c * 8) = ov;
    }
}

extern "C" void kernel_launch(void* const* d_in, const int* in_sizes, int n_in,
                              void* d_out, int out_size, void* d_ws, size_t ws_size,
                              hipStream_t stream) {
    const float* hs = (const float*)d_in[0];
    const float* Wq = (const float*)d_in[1];
    const float* bq = (const float*)d_in[2];
    const float* Wk = (const float*)d_in[3];
    const float* bk = (const float*)d_in[4];
    const float* Wv = (const float*)d_in[5];
    const float* bv = (const float*)d_in[6];
    const float* Wo = (const float*)d_in[7];
    const float* bo = (const float*)d_in[8];
    float* outp = (float*)d_out;
    char* ws = (char*)d_ws;

    // ws layout (88.1 MB total):
    //   Wt   [3072][2048] bf16 : 0          .. 12,582,912
    //   Wot  [2048][2048] bf16 : 12,582,912 .. 20,971,520
    //   bqkv [3072]       f32  : 20,971,520 .. 20,983,808
    //   X    (67,108,864 B)    : 20,983,808 .. 88,092,672   (hs_bf16, then atto)
    bf16_t* Wt     = (bf16_t*)(ws);
    bf16_t* Wot    = (bf16_t*)(ws + 12582912);
    float*  bqkv   = (float*)(ws + 20971520);
    bf16_t* hs_b   = (bf16_t*)(ws + 20983808);
    bf16_t* atto   = (bf16_t*)(ws + 20983808);  // overlays hs_b (dead after QKV gemm)
    // qkv bf16 [16384][3072] = 100.7 MB lives in d_out (134.2 MB fp32) as scratch.
    bf16_t* qkv    = (bf16_t*)d_out;

    // Merged prep: convert + 4 transposes + bias concat in ONE launch.
    prep<<<6668, 256, 0, stream>>>(hs, hs_b, Wq, Wk, Wv, Wo, Wt, Wot, bq, bk, bv, bqkv);

    // QKV projection: [16384,2048] x [2048,3072] -> qkv (bf16, in d_out scratch)
    // grid = 64 Mtiles * 12 Ntiles = 768 (%8==0 -> simple XCD swizzle valid)
    gemm256<bf16_t><<<768, 512, 0, stream>>>(hs_b, 2048, Wt, 2048, bqkv, qkv, 3072, 2048, 12);
    // Grouped attention: 262144 threads = 1024 blocks; one thread per (token,head).
    gqa_attn<<<1024, 256, 0, stream>>>(qkv, 3072, atto, 2048);
    // Output projection -> fp32 d_out ; grid = 64 * 8 = 512 (%8==0)
    gemm256<float><<<512, 512, 0, stream>>>(atto, 2048, Wot, 2048, bo, outp, 2048, 2048, 8);
}

// Round 10
// 621.953 us; speedup vs baseline: 6.2765x; 6.2765x over previous
//
#include <hip/hip_runtime.h>
#include <hip/hip_bf16.h>
#include <stdint.h>

typedef __bf16 bf16_t;
typedef __bf16 bf16x8 __attribute__((ext_vector_type(8)));
typedef __bf16 bf16x4_t __attribute__((ext_vector_type(4)));
typedef float f32x4 __attribute__((ext_vector_type(4)));

#define AS1 __attribute__((address_space(1)))
#define AS3 __attribute__((address_space(3)))

__device__ __forceinline__ void stage16(const bf16_t* g, char* l) {
    __builtin_amdgcn_global_load_lds((const AS1 uint32_t*)g, (AS3 uint32_t*)l, 16, 0, 0);
}

#define BAR()   __builtin_amdgcn_s_barrier()
#define LGKM0() asm volatile("s_waitcnt lgkmcnt(0)" ::: "memory")
#define VMC(N)  asm volatile("s_waitcnt vmcnt(" #N ")" ::: "memory")
#define PRIO(p) __builtin_amdgcn_s_setprio(p)

// ----------------------------------------------------------------------------
// 256x256 SINGLE-BARRIER 8-phase bf16 GEMM (R5/R8 version — FROZEN).
// Best measured: 186 us QKV, MfmaUtil 51%. R9 proved 2-blocks/CU is
// IMPOSSIBLE for this tile: acc[8][4] = 128 regs > the 128-reg budget that
// launch_bounds(512,4) imposes -> full accumulator spill (6.3 GB scratch
// traffic, 13x slowdown). 1 block/CU @ ~51% is this structure's ceiling.
// Ledger: quadrant reads 12/4/4/4; stages P1/P2-P3/P5-P6/P7-P8;
// VMC(4)@P4+P8 certification; LGKM0-pre-barrier protocol.
// ----------------------------------------------------------------------------
template <typename OutT>
__global__ __launch_bounds__(512, 2) void gemm256(
    const bf16_t* __restrict__ A, int lda,
    const bf16_t* __restrict__ Bt, int ldb,
    const float* __restrict__ bias,
    OutT* __restrict__ C, int ldc,
    int K, int nTilesN)
{
    __shared__ char smem[131072];
    const int tid  = threadIdx.x;
    const int wave = tid >> 6;
    const int lane = tid & 63;
    const int wm = wave >> 2;   // 0..1 -> rows wm*128..+128
    const int wn = wave & 3;    // 0..3 -> cols wn*64..+64

    // XCD-aware bijective swizzle (gridDim.x % 8 == 0 guaranteed by caller)
    const int bid = blockIdx.x;
    const int swz = (bid & 7) * ((int)gridDim.x >> 3) + (bid >> 3);
    const int m0 = (swz / nTilesN) << 8;
    const int n0 = (swz % nTilesN) << 8;

    // Staging source: wave w, inst j covers subtile rg=w*2+j; lane's 16B chunk
    // col = (lane&3)*8, XOR 16 when subtile row (lane>>2) bit 3 set (inverse
    // st_16x32 pre-swizzle on the global source address).
    const int srow = lane >> 2;
    const int scol = ((lane & 3) * 8) ^ ((lane & 32) >> 1);
    const bf16_t* aS0 = A  + (size_t)(m0 + wave * 32 + srow) * lda + scol;
    const bf16_t* aS1 = aS0 + (size_t)16 * lda;
    const bf16_t* bS0 = Bt + (size_t)(n0 + wave * 32 + srow) * ldb + scol;
    const bf16_t* bS1 = bS0 + (size_t)16 * ldb;

    // LDS map: A(b,kk) = b*65536 + kk*16384 ; B(b,kk) = +32768.
#define STAGE_A(b,kk,kb) do { \
    stage16(aS0 + (kb) + (kk)*32, smem + (b)*65536 + (kk)*16384 + wave*2048); \
    stage16(aS1 + (kb) + (kk)*32, smem + (b)*65536 + (kk)*16384 + wave*2048 + 1024); } while(0)
#define STAGE_B(b,kk,kb) do { \
    stage16(bS0 + (kb) + (kk)*32, smem + (b)*65536 + 32768 + (kk)*16384 + wave*2048); \
    stage16(bS1 + (kb) + (kk)*32, smem + (b)*65536 + 32768 + (kk)*16384 + wave*2048 + 1024); } while(0)

    // ds_read: lane l -> row l&15, k-chunk (l>>4)*16B, with st_16x32 XOR.
    const int rdLane = (lane & 15) * 64 + (((lane >> 4) * 16) ^ ((lane & 8) << 2));
    const char* aRdB = smem + rdLane + wm * 8192;           // + mi*1024 + A(b,kk)
    const char* bRdB = smem + 32768 + rdLane + wn * 4096;   // + ni*1024 + base(b,kk)

    f32x4 acc[8][4];
#pragma unroll
    for (int i = 0; i < 8; ++i)
#pragma unroll
        for (int j = 0; j < 4; ++j) acc[i][j] = (f32x4){0.f, 0.f, 0.f, 0.f};
    bf16x8 bfr[2][4];   // [kk][ni]; held across the K-tile's 4 phases
    bf16x8 af[2][2];    // [t][kk], current mi-pair

#define RDB8(b) { _Pragma("unroll") \
    for (int kk = 0; kk < 2; ++kk) _Pragma("unroll") \
        for (int ni = 0; ni < 4; ++ni) \
            bfr[kk][ni] = *(const bf16x8*)(bRdB + (b)*65536 + kk*16384 + ni*1024); }
#define RDA(b,mp) { _Pragma("unroll") \
    for (int t = 0; t < 2; ++t) _Pragma("unroll") \
        for (int kk = 0; kk < 2; ++kk) \
            af[t][kk] = *(const bf16x8*)(aRdB + (b)*65536 + kk*16384 + ((mp)*2+t)*1024); }
#define MF(mp) { _Pragma("unroll") \
    for (int t = 0; t < 2; ++t) _Pragma("unroll") \
        for (int ni = 0; ni < 4; ++ni) _Pragma("unroll") \
            for (int kk = 0; kk < 2; ++kk) \
                acc[(mp)*2+t][ni] = __builtin_amdgcn_mfma_f32_16x16x32_bf16(af[t][kk], bfr[kk][ni], acc[(mp)*2+t][ni], 0, 0, 0); }
// Single-barrier phase: stage first (DMA starts earliest), then reads, then
// optional counted vmcnt, then drain reads PRE-barrier, barrier, MFMA.
#define PH(STG, RDS, WAIT, MFM) do { \
    STG; RDS; WAIT; LGKM0(); BAR(); PRIO(1); MFM; PRIO(0); } while(0)

    // Prologue: buf0 A+B @k=0, buf1-B @k=64 (12 loads); drain all; barrier.
    STAGE_A(0, 0, 0);  STAGE_A(0, 1, 0);  STAGE_B(0, 0, 0);  STAGE_B(0, 1, 0);
    STAGE_B(1, 0, 64); STAGE_B(1, 1, 64);
    VMC(0);
    BAR();

    const int NI = K >> 7;
    for (int it = 0; it < NI - 1; ++it) {
        const int kB  = (it << 7) + 64;    // this iter's buf1 (A deferred)
        const int kN0 = (it << 7) + 128;   // next buf0
        const int kN1 = (it << 7) + 192;   // next buf1
        PH(STAGE_A(1,0,kB); STAGE_A(1,1,kB), RDB8(0); RDA(0,0), , MF(0));
        PH(STAGE_B(0,0,kN0),                 RDA(0,1),          , MF(1));
        PH(STAGE_B(0,1,kN0),                 RDA(0,2),          , MF(2));
        PH(,                                 RDA(0,3),    VMC(4), MF(3));
        PH(STAGE_A(0,0,kN0),                 RDB8(1); RDA(1,0), , MF(0));
        PH(STAGE_A(0,1,kN0),                 RDA(1,1),          , MF(1));
        PH(STAGE_B(1,0,kN1),                 RDA(1,2),          , MF(2));
        PH(STAGE_B(1,1,kN1),                 RDA(1,3),    VMC(4), MF(3));
    }
    // Epilogue iteration: buf1-A still staged at P1; nothing else.
    {
        const int kB = ((NI - 1) << 7) + 64;
        PH(STAGE_A(1,0,kB); STAGE_A(1,1,kB), RDB8(0); RDA(0,0), , MF(0));
        PH(,                                 RDA(0,1),          , MF(1));
        PH(,                                 RDA(0,2),          , MF(2));
        PH(,                                 RDA(0,3),    VMC(0), MF(3));
        PH(,                                 RDB8(1); RDA(1,0), , MF(0));
        PH(,                                 RDA(1,1),          , MF(1));
        PH(,                                 RDA(1,2),          , MF(2));
        PH(,                                 RDA(1,3),          , MF(3));
    }
    BAR();

    // ---- Epilogue: LDS-staged coalesced C write (two 128-row halves) ----
    // Write-in swizzle: colb ^= quad*16*CSZ; readback applies same XOR.
    {
        const int mrow = lane & 15;
        const int quad = lane >> 4;
        constexpr int CSZ = (int)sizeof(OutT);
        float bias_v[4];
#pragma unroll
        for (int ni = 0; ni < 4; ++ni)
            bias_v[ni] = bias[n0 + wn * 64 + ni * 16 + mrow];
#pragma unroll
        for (int h = 0; h < 2; ++h) {
            if (wm == h) {
#pragma unroll
                for (int ni = 0; ni < 4; ++ni) {
                    const int colb = (wn * 64 + ni * 16 + mrow) * CSZ;
#pragma unroll
                    for (int mi = 0; mi < 8; ++mi)
#pragma unroll
                        for (int r = 0; r < 4; ++r) {
                            const int lrow = mi * 16 + quad * 4 + r;
                            *(OutT*)(smem + lrow * 256 * CSZ + (colb ^ (quad * 16 * CSZ))) =
                                (OutT)(acc[mi][ni][r] + bias_v[ni]);
                        }
                }
            }
            BAR();
            const int ROUNDS = 128 * 256 * CSZ / 8192;
#pragma unroll
            for (int rd = 0; rd < ROUNDS; ++rd) {
                const int flat = rd * 8192 + tid * 16;
                const int lrow = flat / (256 * CSZ);
                const int colb = flat % (256 * CSZ);
                const int q2 = (lrow >> 2) & 3;
                uint4 v = *(const uint4*)(smem + lrow * 256 * CSZ + (colb ^ (q2 * 16 * CSZ)));
                *(uint4*)((char*)C + ((size_t)(m0 + h * 128 + lrow) * ldc + n0) * CSZ + colb) = v;
            }
            BAR();
        }
    }
#undef STAGE_A
#undef STAGE_B
#undef RDB8
#undef RDA
#undef MF
#undef PH
}

// ----------------------------------------------------------------------------
// Merged prep: ONE launch (f32->bf16 + 4 transposes + concat_bias). R8-verified.
// ----------------------------------------------------------------------------
__global__ __launch_bounds__(256) void prep(
    const float* __restrict__ hs, bf16_t* __restrict__ hs_b,
    const float* __restrict__ Wq, const float* __restrict__ Wk,
    const float* __restrict__ Wv, const float* __restrict__ Wo,
    bf16_t* __restrict__ Wt, bf16_t* __restrict__ Wot,
    const float* __restrict__ bq, const float* __restrict__ bk,
    const float* __restrict__ bv, float* __restrict__ bqkv)
{
    __shared__ bf16_t t[64][65];
    const int b = blockIdx.x;
    if (b < 4096) {
        size_t i = (size_t)b * 256 + threadIdx.x;
#pragma unroll
        for (int r = 0; r < 8; ++r, i += 1048576) {
            float4 v = ((const float4*)hs)[i];
            bf16x4_t o;
            o.x = (bf16_t)v.x; o.y = (bf16_t)v.y; o.z = (bf16_t)v.z; o.w = (bf16_t)v.w;
            ((bf16x4_t*)hs_b)[i] = o;
        }
        return;
    }
    if (b >= 6656) {
        int i = (b - 6656) * 256 + threadIdx.x;
        if (i < 3072) bqkv[i] = (i < 2048) ? bq[i] : (i < 2560 ? bk[i - 2048] : bv[i - 2560]);
        return;
    }
    const float* src; bf16_t* dst; int cols, bx, by;
    if (b < 5120)      { src = Wq; dst = Wt;                     cols = 2048; int u = b - 4096; bx = u & 31; by = u >> 5; }
    else if (b < 5376) { src = Wk; dst = Wt + (size_t)2048*2048; cols = 512;  int u = b - 5120; bx = u & 7;  by = u >> 3; }
    else if (b < 5632) { src = Wv; dst = Wt + (size_t)2560*2048; cols = 512;  int u = b - 5376; bx = u & 7;  by = u >> 3; }
    else               { src = Wo; dst = Wot;                    cols = 2048; int u = b - 5632; bx = u & 31; by = u >> 5; }
    const int rows = 2048;
    const int tx = threadIdx.x & 63;
    const int ty = threadIdx.x >> 6;
    const int c0 = bx * 64;
    const int r0 = by * 64;
#pragma unroll
    for (int r = ty; r < 64; r += 4)
        t[r][tx] = (bf16_t)src[(size_t)(r0 + r) * cols + c0 + tx];
    __syncthreads();
#pragma unroll
    for (int r = ty; r < 64; r += 4)
        dst[(size_t)(c0 + r) * rows + r0 + tx] = t[tx][r];
}

// ----------------------------------------------------------------------------
// LDS-staged grouped attention. R9 diagnosis: per-thread version issued ~145
// global 16B loads/thread with k/v 16x-DUPLICATED across the 16 heads of a
// token (~42M VMEM instrs total) -> VMEM-issue bound. Fix: block = 16 tokens;
// stage k+v (2KB/token = 32KB) into LDS with 8 coalesced global_load_lds per
// thread; score/PV read k/v from LDS (16 heads hit the SAME address ->
// broadcast, free; 4 tokens/wave -> 4 distinct addrs, conflict-free).
// Global VMEM instrs/thread: 145 -> 40. Zero cross-lane ops.
// Writes compact [16384][2048] (so=2048).
// ----------------------------------------------------------------------------
__global__ __launch_bounds__(256) void gqa_attn(
    const bf16_t* __restrict__ qkv, int sq,
    bf16_t* __restrict__ out, int so)
{
    __shared__ bf16_t kvs[16 * 1024];   // 32 KB: token t -> k at [t*1024], v at [t*1024+512]
    const int tid  = threadIdx.x;
    const int tok0 = blockIdx.x * 16;

    // Stage k+v for 16 tokens: 2048 chunks of 16B; thread stages 8 strided
    // rounds (round r, chunk c = r*256+tid). LDS dest = uniform (r,wave) base
    // + lane*16 (hardware). Global src per-lane (token = c>>7, off = c&127).
#pragma unroll
    for (int r = 0; r < 8; ++r) {
        const int c = r * 256 + tid;
        stage16(qkv + (size_t)(tok0 + (c >> 7)) * sq + 2048 + (c & 127) * 8,
                (char*)kvs + r * 4096 + (tid >> 6) * 1024);
    }
    VMC(0);
    __syncthreads();

    const int tl = tid >> 4;          // local token 0..15
    const int h  = tid & 15;          // head
    const bf16_t* kl = kvs + tl * 1024;
    const bf16_t* vl = kl + 512;
    const bf16_t* qb = qkv + (size_t)(tok0 + tl) * sq + h * 128;
    const float scale = 0.08838834764831845f;  // 1/sqrt(128)

    float s[4] = {0.f, 0.f, 0.f, 0.f};
#pragma unroll 4
    for (int c = 0; c < 16; ++c) {
        const uint4 qv = *(const uint4*)(qb + c * 8);
        const uint32_t qa[4] = {qv.x, qv.y, qv.z, qv.w};
#pragma unroll
        for (int g = 0; g < 4; ++g) {
            const uint4 kv4 = *(const uint4*)(kl + g * 128 + c * 8);
            const uint32_t ka[4] = {kv4.x, kv4.y, kv4.z, kv4.w};
#pragma unroll
            for (int w = 0; w < 4; ++w) {
                s[g] += __uint_as_float(qa[w] << 16) * __uint_as_float(ka[w] << 16);
                s[g] += __uint_as_float(qa[w] & 0xffff0000u) * __uint_as_float(ka[w] & 0xffff0000u);
            }
        }
    }
    const float mx = fmaxf(fmaxf(s[0], s[1]), fmaxf(s[2], s[3]));
    float p[4], sum = 0.f;
#pragma unroll
    for (int g = 0; g < 4; ++g) { p[g] = __expf((s[g] - mx) * scale); sum += p[g]; }
    const float rs = 1.0f / sum;
#pragma unroll
    for (int g = 0; g < 4; ++g) p[g] *= rs;

    bf16_t* ob = out + (size_t)(tok0 + tl) * so + h * 128;
#pragma unroll 4
    for (int c = 0; c < 16; ++c) {
        float o0[8] = {0.f, 0.f, 0.f, 0.f, 0.f, 0.f, 0.f, 0.f};
#pragma unroll
        for (int g = 0; g < 4; ++g) {
            const uint4 vv = *(const uint4*)(vl + g * 128 + c * 8);
            const uint32_t va[4] = {vv.x, vv.y, vv.z, vv.w};
#pragma unroll
            for (int w = 0; w < 4; ++w) {
                o0[w * 2]     += p[g] * __uint_as_float(va[w] << 16);
                o0[w * 2 + 1] += p[g] * __uint_as_float(va[w] & 0xffff0000u);
            }
        }
        bf16x8 ov;
#pragma unroll
        for (int j = 0; j < 8; ++j) ov[j] = (bf16_t)o0[j];
        *(bf16x8*)(ob + c * 8) = ov;
    }
}

extern "C" void kernel_launch(void* const* d_in, const int* in_sizes, int n_in,
                              void* d_out, int out_size, void* d_ws, size_t ws_size,
                              hipStream_t stream) {
    const float* hs = (const float*)d_in[0];
    const float* Wq = (const float*)d_in[1];
    const float* bq = (const float*)d_in[2];
    const float* Wk = (const float*)d_in[3];
    const float* bk = (const float*)d_in[4];
    const float* Wv = (const float*)d_in[5];
    const float* bv = (const float*)d_in[6];
    const float* Wo = (const float*)d_in[7];
    const float* bo = (const float*)d_in[8];
    float* outp = (float*)d_out;
    char* ws = (char*)d_ws;

    // ws layout (88.1 MB total):
    //   Wt   [3072][2048] bf16 : 0          .. 12,582,912
    //   Wot  [2048][2048] bf16 : 12,582,912 .. 20,971,520
    //   bqkv [3072]       f32  : 20,971,520 .. 20,983,808
    //   X    (67,108,864 B)    : 20,983,808 .. 88,092,672   (hs_bf16, then atto)
    bf16_t* Wt     = (bf16_t*)(ws);
    bf16_t* Wot    = (bf16_t*)(ws + 12582912);
    float*  bqkv   = (float*)(ws + 20971520);
    bf16_t* hs_b   = (bf16_t*)(ws + 20983808);
    bf16_t* atto   = (bf16_t*)(ws + 20983808);  // overlays hs_b (dead after QKV gemm)
    // qkv bf16 [16384][3072] = 100.7 MB lives in d_out (134.2 MB fp32) as scratch.
    bf16_t* qkv    = (bf16_t*)d_out;

    // Merged prep: convert + 4 transposes + bias concat in ONE launch.
    prep<<<6668, 256, 0, stream>>>(hs, hs_b, Wq, Wk, Wv, Wo, Wt, Wot, bq, bk, bv, bqkv);

    // QKV projection: [16384,2048] x [2048,3072] -> qkv (bf16, in d_out scratch)
    // grid = 64 Mtiles * 12 Ntiles = 768 (%8==0 -> simple XCD swizzle valid)
    gemm256<bf16_t><<<768, 512, 0, stream>>>(hs_b, 2048, Wt, 2048, bqkv, qkv, 3072, 2048, 12);
    // Grouped attention: 1024 blocks x 16 tokens, LDS-staged k/v.
    gqa_attn<<<1024, 256, 0, stream>>>(qkv, 3072, atto, 2048);
    // Output projection -> fp32 d_out ; grid = 64 * 8 = 512 (%8==0)
    gemm256<float><<<512, 512, 0, stream>>>(atto, 2048, Wot, 2048, bo, outp, 2048, 2048, 8);
}

// Round 11
// 610.312 us; speedup vs baseline: 6.3962x; 1.0191x over previous
//
#include <hip/hip_runtime.h>
#include <hip/hip_bf16.h>
#include <stdint.h>

typedef __bf16 bf16_t;
typedef __bf16 bf16x8 __attribute__((ext_vector_type(8)));
typedef __bf16 bf16x4_t __attribute__((ext_vector_type(4)));
typedef float f32x4 __attribute__((ext_vector_type(4)));

#define AS1 __attribute__((address_space(1)))
#define AS3 __attribute__((address_space(3)))

__device__ __forceinline__ void stage16(const bf16_t* g, char* l) {
    __builtin_amdgcn_global_load_lds((const AS1 uint32_t*)g, (AS3 uint32_t*)l, 16, 0, 0);
}

#define BAR()   __builtin_amdgcn_s_barrier()
#define LGKM0() asm volatile("s_waitcnt lgkmcnt(0)" ::: "memory")
#define VMC(N)  asm volatile("s_waitcnt vmcnt(" #N ")" ::: "memory")
#define PRIO(p) __builtin_amdgcn_s_setprio(p)

// ----------------------------------------------------------------------------
// 256x256 SINGLE-BARRIER 8-phase bf16 GEMM (R5/R8 version — FROZEN).
// Best measured: 186 us QKV, MfmaUtil ~51%. Structural notes:
//  - R9 proved 2-blocks/CU impossible: acc[8][4] = 128 regs > the 128-reg
//    budget launch_bounds(512,4) imposes -> full accumulator spill (13x).
//  - R5 (single-barrier) = R3 (2-barrier) = 48-51%: phase-locked waves
//    alternate LDS and MFMA pipes globally; 4 schedule variants plateau here.
// Ledger: quadrant reads 12/4/4/4; stages P1/P2-P3/P5-P6/P7-P8;
// VMC(4)@P4+P8 certification; LGKM0-pre-barrier protocol.
// ----------------------------------------------------------------------------
template <typename OutT>
__global__ __launch_bounds__(512, 2) void gemm256(
    const bf16_t* __restrict__ A, int lda,
    const bf16_t* __restrict__ Bt, int ldb,
    const float* __restrict__ bias,
    OutT* __restrict__ C, int ldc,
    int K, int nTilesN)
{
    __shared__ char smem[131072];
    const int tid  = threadIdx.x;
    const int wave = tid >> 6;
    const int lane = tid & 63;
    const int wm = wave >> 2;   // 0..1 -> rows wm*128..+128
    const int wn = wave & 3;    // 0..3 -> cols wn*64..+64

    // XCD-aware bijective swizzle (gridDim.x % 8 == 0 guaranteed by caller)
    const int bid = blockIdx.x;
    const int swz = (bid & 7) * ((int)gridDim.x >> 3) + (bid >> 3);
    const int m0 = (swz / nTilesN) << 8;
    const int n0 = (swz % nTilesN) << 8;

    // Staging source: wave w, inst j covers subtile rg=w*2+j; lane's 16B chunk
    // col = (lane&3)*8, XOR 16 when subtile row (lane>>2) bit 3 set (inverse
    // st_16x32 pre-swizzle on the global source address).
    const int srow = lane >> 2;
    const int scol = ((lane & 3) * 8) ^ ((lane & 32) >> 1);
    const bf16_t* aS0 = A  + (size_t)(m0 + wave * 32 + srow) * lda + scol;
    const bf16_t* aS1 = aS0 + (size_t)16 * lda;
    const bf16_t* bS0 = Bt + (size_t)(n0 + wave * 32 + srow) * ldb + scol;
    const bf16_t* bS1 = bS0 + (size_t)16 * ldb;

    // LDS map: A(b,kk) = b*65536 + kk*16384 ; B(b,kk) = +32768.
#define STAGE_A(b,kk,kb) do { \
    stage16(aS0 + (kb) + (kk)*32, smem + (b)*65536 + (kk)*16384 + wave*2048); \
    stage16(aS1 + (kb) + (kk)*32, smem + (b)*65536 + (kk)*16384 + wave*2048 + 1024); } while(0)
#define STAGE_B(b,kk,kb) do { \
    stage16(bS0 + (kb) + (kk)*32, smem + (b)*65536 + 32768 + (kk)*16384 + wave*2048); \
    stage16(bS1 + (kb) + (kk)*32, smem + (b)*65536 + 32768 + (kk)*16384 + wave*2048 + 1024); } while(0)

    // ds_read: lane l -> row l&15, k-chunk (l>>4)*16B, with st_16x32 XOR.
    const int rdLane = (lane & 15) * 64 + (((lane >> 4) * 16) ^ ((lane & 8) << 2));
    const char* aRdB = smem + rdLane + wm * 8192;           // + mi*1024 + A(b,kk)
    const char* bRdB = smem + 32768 + rdLane + wn * 4096;   // + ni*1024 + base(b,kk)

    f32x4 acc[8][4];
#pragma unroll
    for (int i = 0; i < 8; ++i)
#pragma unroll
        for (int j = 0; j < 4; ++j) acc[i][j] = (f32x4){0.f, 0.f, 0.f, 0.f};
    bf16x8 bfr[2][4];   // [kk][ni]; held across the K-tile's 4 phases
    bf16x8 af[2][2];    // [t][kk], current mi-pair

#define RDB8(b) { _Pragma("unroll") \
    for (int kk = 0; kk < 2; ++kk) _Pragma("unroll") \
        for (int ni = 0; ni < 4; ++ni) \
            bfr[kk][ni] = *(const bf16x8*)(bRdB + (b)*65536 + kk*16384 + ni*1024); }
#define RDA(b,mp) { _Pragma("unroll") \
    for (int t = 0; t < 2; ++t) _Pragma("unroll") \
        for (int kk = 0; kk < 2; ++kk) \
            af[t][kk] = *(const bf16x8*)(aRdB + (b)*65536 + kk*16384 + ((mp)*2+t)*1024); }
#define MF(mp) { _Pragma("unroll") \
    for (int t = 0; t < 2; ++t) _Pragma("unroll") \
        for (int ni = 0; ni < 4; ++ni) _Pragma("unroll") \
            for (int kk = 0; kk < 2; ++kk) \
                acc[(mp)*2+t][ni] = __builtin_amdgcn_mfma_f32_16x16x32_bf16(af[t][kk], bfr[kk][ni], acc[(mp)*2+t][ni], 0, 0, 0); }
// Single-barrier phase: stage first (DMA starts earliest), then reads, then
// optional counted vmcnt, then drain reads PRE-barrier, barrier, MFMA.
#define PH(STG, RDS, WAIT, MFM) do { \
    STG; RDS; WAIT; LGKM0(); BAR(); PRIO(1); MFM; PRIO(0); } while(0)

    // Prologue: buf0 A+B @k=0, buf1-B @k=64 (12 loads); drain all; barrier.
    STAGE_A(0, 0, 0);  STAGE_A(0, 1, 0);  STAGE_B(0, 0, 0);  STAGE_B(0, 1, 0);
    STAGE_B(1, 0, 64); STAGE_B(1, 1, 64);
    VMC(0);
    BAR();

    const int NI = K >> 7;
    for (int it = 0; it < NI - 1; ++it) {
        const int kB  = (it << 7) + 64;    // this iter's buf1 (A deferred)
        const int kN0 = (it << 7) + 128;   // next buf0
        const int kN1 = (it << 7) + 192;   // next buf1
        PH(STAGE_A(1,0,kB); STAGE_A(1,1,kB), RDB8(0); RDA(0,0), , MF(0));
        PH(STAGE_B(0,0,kN0),                 RDA(0,1),          , MF(1));
        PH(STAGE_B(0,1,kN0),                 RDA(0,2),          , MF(2));
        PH(,                                 RDA(0,3),    VMC(4), MF(3));
        PH(STAGE_A(0,0,kN0),                 RDB8(1); RDA(1,0), , MF(0));
        PH(STAGE_A(0,1,kN0),                 RDA(1,1),          , MF(1));
        PH(STAGE_B(1,0,kN1),                 RDA(1,2),          , MF(2));
        PH(STAGE_B(1,1,kN1),                 RDA(1,3),    VMC(4), MF(3));
    }
    // Epilogue iteration: buf1-A still staged at P1; nothing else.
    {
        const int kB = ((NI - 1) << 7) + 64;
        PH(STAGE_A(1,0,kB); STAGE_A(1,1,kB), RDB8(0); RDA(0,0), , MF(0));
        PH(,                                 RDA(0,1),          , MF(1));
        PH(,                                 RDA(0,2),          , MF(2));
        PH(,                                 RDA(0,3),    VMC(0), MF(3));
        PH(,                                 RDB8(1); RDA(1,0), , MF(0));
        PH(,                                 RDA(1,1),          , MF(1));
        PH(,                                 RDA(1,2),          , MF(2));
        PH(,                                 RDA(1,3),          , MF(3));
    }
    BAR();

    // ---- Epilogue: LDS-staged coalesced C write (two 128-row halves) ----
    // Write-in swizzle: colb ^= quad*16*CSZ; readback applies same XOR.
    {
        const int mrow = lane & 15;
        const int quad = lane >> 4;
        constexpr int CSZ = (int)sizeof(OutT);
        float bias_v[4];
#pragma unroll
        for (int ni = 0; ni < 4; ++ni)
            bias_v[ni] = bias[n0 + wn * 64 + ni * 16 + mrow];
#pragma unroll
        for (int h = 0; h < 2; ++h) {
            if (wm == h) {
#pragma unroll
                for (int ni = 0; ni < 4; ++ni) {
                    const int colb = (wn * 64 + ni * 16 + mrow) * CSZ;
#pragma unroll
                    for (int mi = 0; mi < 8; ++mi)
#pragma unroll
                        for (int r = 0; r < 4; ++r) {
                            const int lrow = mi * 16 + quad * 4 + r;
                            *(OutT*)(smem + lrow * 256 * CSZ + (colb ^ (quad * 16 * CSZ))) =
                                (OutT)(acc[mi][ni][r] + bias_v[ni]);
                        }
                }
            }
            BAR();
            const int ROUNDS = 128 * 256 * CSZ / 8192;
#pragma unroll
            for (int rd = 0; rd < ROUNDS; ++rd) {
                const int flat = rd * 8192 + tid * 16;
                const int lrow = flat / (256 * CSZ);
                const int colb = flat % (256 * CSZ);
                const int q2 = (lrow >> 2) & 3;
                uint4 v = *(const uint4*)(smem + lrow * 256 * CSZ + (colb ^ (q2 * 16 * CSZ)));
                *(uint4*)((char*)C + ((size_t)(m0 + h * 128 + lrow) * ldc + n0) * CSZ + colb) = v;
            }
            BAR();
        }
    }
#undef STAGE_A
#undef STAGE_B
#undef RDB8
#undef RDA
#undef MF
#undef PH
}

// ----------------------------------------------------------------------------
// Merged prep: ONE launch (f32->bf16 + 4 transposes + concat_bias). R8-verified.
// ----------------------------------------------------------------------------
__global__ __launch_bounds__(256) void prep(
    const float* __restrict__ hs, bf16_t* __restrict__ hs_b,
    const float* __restrict__ Wq, const float* __restrict__ Wk,
    const float* __restrict__ Wv, const float* __restrict__ Wo,
    bf16_t* __restrict__ Wt, bf16_t* __restrict__ Wot,
    const float* __restrict__ bq, const float* __restrict__ bk,
    const float* __restrict__ bv, float* __restrict__ bqkv)
{
    __shared__ bf16_t t[64][65];
    const int b = blockIdx.x;
    if (b < 4096) {
        size_t i = (size_t)b * 256 + threadIdx.x;
#pragma unroll
        for (int r = 0; r < 8; ++r, i += 1048576) {
            float4 v = ((const float4*)hs)[i];
            bf16x4_t o;
            o.x = (bf16_t)v.x; o.y = (bf16_t)v.y; o.z = (bf16_t)v.z; o.w = (bf16_t)v.w;
            ((bf16x4_t*)hs_b)[i] = o;
        }
        return;
    }
    if (b >= 6656) {
        int i = (b - 6656) * 256 + threadIdx.x;
        if (i < 3072) bqkv[i] = (i < 2048) ? bq[i] : (i < 2560 ? bk[i - 2048] : bv[i - 2560]);
        return;
    }
    const float* src; bf16_t* dst; int cols, bx, by;
    if (b < 5120)      { src = Wq; dst = Wt;                     cols = 2048; int u = b - 4096; bx = u & 31; by = u >> 5; }
    else if (b < 5376) { src = Wk; dst = Wt + (size_t)2048*2048; cols = 512;  int u = b - 5120; bx = u & 7;  by = u >> 3; }
    else if (b < 5632) { src = Wv; dst = Wt + (size_t)2560*2048; cols = 512;  int u = b - 5376; bx = u & 7;  by = u >> 3; }
    else               { src = Wo; dst = Wot;                    cols = 2048; int u = b - 5632; bx = u & 31; by = u >> 5; }
    const int rows = 2048;
    const int tx = threadIdx.x & 63;
    const int ty = threadIdx.x >> 6;
    const int c0 = bx * 64;
    const int r0 = by * 64;
#pragma unroll
    for (int r = ty; r < 64; r += 4)
        t[r][tx] = (bf16_t)src[(size_t)(r0 + r) * cols + c0 + tx];
    __syncthreads();
#pragma unroll
    for (int r = ty; r < 64; r += 4)
        dst[(size_t)(c0 + r) * rows + r0 + tx] = t[tx][r];
}

// ----------------------------------------------------------------------------
// Shuffle-free grouped attention: ONE THREAD per (token, head) — R8 version,
// measured-best. R10's LDS-staged variant was +14us (staging barrier serializes;
// L1 already absorbs the 16x k/v duplication via broadcast). Zero cross-lane
// ops, zero LDS. Writes compact [16384][2048] (so=2048).
// ----------------------------------------------------------------------------
__global__ __launch_bounds__(256) void gqa_attn(
    const bf16_t* __restrict__ qkv, int sq,
    bf16_t* __restrict__ out, int so)
{
    const int t = blockIdx.x * 256 + threadIdx.x;
    const int token = t >> 4;
    const int h = t & 15;
    const bf16_t* qb = qkv + (size_t)token * sq + h * 128;
    const bf16_t* kb = qkv + (size_t)token * sq + 2048;
    const bf16_t* vb = kb + 512;
    const float scale = 0.08838834764831845f;  // 1/sqrt(128)

    float s[4] = {0.f, 0.f, 0.f, 0.f};
#pragma unroll 4
    for (int c = 0; c < 16; ++c) {
        const uint4 qv = *(const uint4*)(qb + c * 8);
        const uint32_t qa[4] = {qv.x, qv.y, qv.z, qv.w};
#pragma unroll
        for (int g = 0; g < 4; ++g) {
            const uint4 kv4 = *(const uint4*)(kb + g * 128 + c * 8);
            const uint32_t ka[4] = {kv4.x, kv4.y, kv4.z, kv4.w};
#pragma unroll
            for (int w = 0; w < 4; ++w) {
                s[g] += __uint_as_float(qa[w] << 16) * __uint_as_float(ka[w] << 16);
                s[g] += __uint_as_float(qa[w] & 0xffff0000u) * __uint_as_float(ka[w] & 0xffff0000u);
            }
        }
    }
    const float mx = fmaxf(fmaxf(s[0], s[1]), fmaxf(s[2], s[3]));
    float p[4], sum = 0.f;
#pragma unroll
    for (int g = 0; g < 4; ++g) { p[g] = __expf((s[g] - mx) * scale); sum += p[g]; }
    const float rs = 1.0f / sum;
#pragma unroll
    for (int g = 0; g < 4; ++g) p[g] *= rs;

    bf16_t* ob = out + (size_t)token * so + h * 128;
#pragma unroll 4
    for (int c = 0; c < 16; ++c) {
        float o0[8] = {0.f, 0.f, 0.f, 0.f, 0.f, 0.f, 0.f, 0.f};
#pragma unroll
        for (int g = 0; g < 4; ++g) {
            const uint4 vv = *(const uint4*)(vb + g * 128 + c * 8);
            const uint32_t va[4] = {vv.x, vv.y, vv.z, vv.w};
#pragma unroll
            for (int w = 0; w < 4; ++w) {
                o0[w * 2]     += p[g] * __uint_as_float(va[w] << 16);
                o0[w * 2 + 1] += p[g] * __uint_as_float(va[w] & 0xffff0000u);
            }
        }
        bf16x8 ov;
#pragma unroll
        for (int j = 0; j < 8; ++j) ov[j] = (bf16_t)o0[j];
        *(bf16x8*)(ob + c * 8) = ov;
    }
}

extern "C" void kernel_launch(void* const* d_in, const int* in_sizes, int n_in,
                              void* d_out, int out_size, void* d_ws, size_t ws_size,
                              hipStream_t stream) {
    const float* hs = (const float*)d_in[0];
    const float* Wq = (const float*)d_in[1];
    const float* bq = (const float*)d_in[2];
    const float* Wk = (const float*)d_in[3];
    const float* bk = (const float*)d_in[4];
    const float* Wv = (const float*)d_in[5];
    const float* bv = (const float*)d_in[6];
    const float* Wo = (const float*)d_in[7];
    const float* bo = (const float*)d_in[8];
    float* outp = (float*)d_out;
    char* ws = (char*)d_ws;

    // ws layout (88.1 MB total):
    //   Wt   [3072][2048] bf16 : 0          .. 12,582,912
    //   Wot  [2048][2048] bf16 : 12,582,912 .. 20,971,520
    //   bqkv [3072]       f32  : 20,971,520 .. 20,983,808
    //   X    (67,108,864 B)    : 20,983,808 .. 88,092,672   (hs_bf16, then atto)
    bf16_t* Wt     = (bf16_t*)(ws);
    bf16_t* Wot    = (bf16_t*)(ws + 12582912);
    float*  bqkv   = (float*)(ws + 20971520);
    bf16_t* hs_b   = (bf16_t*)(ws + 20983808);
    bf16_t* atto   = (bf16_t*)(ws + 20983808);  // overlays hs_b (dead after QKV gemm)
    // qkv bf16 [16384][3072] = 100.7 MB lives in d_out (134.2 MB fp32) as scratch.
    bf16_t* qkv    = (bf16_t*)d_out;

    // Merged prep: convert + 4 transposes + bias concat in ONE launch.
    prep<<<6668, 256, 0, stream>>>(hs, hs_b, Wq, Wk, Wv, Wo, Wt, Wot, bq, bk, bv, bqkv);

    // QKV projection: [16384,2048] x [2048,3072] -> qkv (bf16, in d_out scratch)
    // grid = 64 Mtiles * 12 Ntiles = 768 (%8==0 -> simple XCD swizzle valid)
    gemm256<bf16_t><<<768, 512, 0, stream>>>(hs_b, 2048, Wt, 2048, bqkv, qkv, 3072, 2048, 12);
    // Grouped attention: 262144 threads = 1024 blocks; one thread per (token,head).
    gqa_attn<<<1024, 256, 0, stream>>>(qkv, 3072, atto, 2048);
    // Output projection -> fp32 d_out ; grid = 64 * 8 = 512 (%8==0)
    gemm256<float><<<512, 512, 0, stream>>>(atto, 2048, Wot, 2048, bo, outp, 2048, 2048, 8);
}